// Round 1
// baseline (3343.010 us; speedup 1.0000x reference)
//
#include <hip/hip_runtime.h>
#include <hip/hip_bf16.h>

#define Hh   64      // LSTM hidden
#define G4   256     // 4*H gate width
#define Dd   128     // input feature dim
#define Bsz  256     // batch
#define Tt   1024    // time steps
#define NOUT 10      // dense classes

// ---------------------------------------------------------------------------
// K1: xw[b,t,g] = bias[g] + sum_k x[b,t,k] * W[k,g]   (store bf16)
// thread g = output column (0..255). W column cached in 128 VGPRs.
// x row addresses are wave-uniform -> scalar loads. RB rows per block.
// ---------------------------------------------------------------------------
#define RB 16

__global__ __launch_bounds__(256)
void k1_xw(const float* __restrict__ x, const float* __restrict__ W,
           const float* __restrict__ bias, __hip_bfloat16* __restrict__ xw) {
    const int g = threadIdx.x;
    const size_t rowbase = (size_t)blockIdx.x * RB;

    // W column into registers
    float w[Dd];
#pragma unroll
    for (int k = 0; k < Dd; ++k) w[k] = W[(size_t)k * G4 + g];
    const float bg = bias[g];

    for (int r = 0; r < RB; ++r) {
        const float* __restrict__ xr = x + (rowbase + r) * Dd;  // uniform ptr
        float a0 = bg, a1 = 0.f, a2 = 0.f, a3 = 0.f;
#pragma unroll
        for (int k = 0; k < Dd; k += 4) {
            a0 = fmaf(xr[k + 0], w[k + 0], a0);
            a1 = fmaf(xr[k + 1], w[k + 1], a1);
            a2 = fmaf(xr[k + 2], w[k + 2], a2);
            a3 = fmaf(xr[k + 3], w[k + 3], a3);
        }
        float acc = (a0 + a1) + (a2 + a3);
        xw[(rowbase + r) * G4 + g] = __float2bfloat16(acc);
    }
}

// ---------------------------------------------------------------------------
// K2: sequential LSTM scan. One workgroup (256 threads) per batch row.
// Thread g owns U column g (64 VGPRs). h broadcast via LDS; z via LDS;
// lanes < 64 keep c in a register and apply the gates.
// ---------------------------------------------------------------------------
__global__ __launch_bounds__(256)
void k2_scan(const __hip_bfloat16* __restrict__ xw, const float* __restrict__ U,
             float* __restrict__ hout) {
    const int g = threadIdx.x;
    const int brow = blockIdx.x;

    __shared__ float hs[Hh];
    __shared__ float zs[G4];

    float u[Hh];
#pragma unroll
    for (int j = 0; j < Hh; ++j) u[j] = U[(size_t)j * G4 + g];

    float c = 0.f;
    if (g < Hh) hs[g] = 0.f;
    __syncthreads();

    const __hip_bfloat16* __restrict__ xwrow = xw + (size_t)brow * Tt * G4;

    for (int t = 0; t < Tt; ++t) {
        float z = __bfloat162float(xwrow[(size_t)t * G4 + g]);
        float a0 = 0.f, a1 = 0.f, a2 = 0.f, a3 = 0.f;
#pragma unroll
        for (int j = 0; j < Hh; j += 4) {
            a0 = fmaf(hs[j + 0], u[j + 0], a0);
            a1 = fmaf(hs[j + 1], u[j + 1], a1);
            a2 = fmaf(hs[j + 2], u[j + 2], a2);
            a3 = fmaf(hs[j + 3], u[j + 3], a3);
        }
        z += (a0 + a1) + (a2 + a3);
        zs[g] = z;
        __syncthreads();
        if (g < Hh) {
            float zi = zs[g], zf = zs[Hh + g], zg = zs[2 * Hh + g], zo = zs[3 * Hh + g];
            float gi = fminf(fmaxf(0.2f * zi + 0.5f, 0.f), 1.f);
            float gf = fminf(fmaxf(0.2f * zf + 0.5f, 0.f), 1.f);
            float gg = fmaxf(zg, 0.f);
            float go = fminf(fmaxf(0.2f * zo + 0.5f, 0.f), 1.f);
            c = gf * c + gi * gg;
            hs[g] = go * fmaxf(c, 0.f);
        }
        __syncthreads();
    }
    if (g < Hh) hout[(size_t)brow * Hh + g] = hs[g];
}

// ---------------------------------------------------------------------------
// K3: out[r,:] = softmax(h[r,:] @ Wd + bd). One block, thread = batch row.
// ---------------------------------------------------------------------------
__global__ __launch_bounds__(256)
void k3_dense(const float* __restrict__ hin, const float* __restrict__ Wd,
              const float* __restrict__ bd, float* __restrict__ out) {
    __shared__ float wd[Hh * NOUT];
    __shared__ float bds[NOUT];
    for (int i = threadIdx.x; i < Hh * NOUT; i += blockDim.x) wd[i] = Wd[i];
    if (threadIdx.x < NOUT) bds[threadIdx.x] = bd[threadIdx.x];
    __syncthreads();

    const int r = threadIdx.x;
    if (r < Bsz) {
        float hrow[Hh];
#pragma unroll
        for (int j = 0; j < Hh; ++j) hrow[j] = hin[(size_t)r * Hh + j];
        float logits[NOUT];
#pragma unroll
        for (int o = 0; o < NOUT; ++o) {
            float acc = bds[o];
#pragma unroll
            for (int j = 0; j < Hh; ++j) acc = fmaf(hrow[j], wd[j * NOUT + o], acc);
            logits[o] = acc;
        }
        float m = logits[0];
#pragma unroll
        for (int o = 1; o < NOUT; ++o) m = fmaxf(m, logits[o]);
        float s = 0.f;
#pragma unroll
        for (int o = 0; o < NOUT; ++o) { logits[o] = expf(logits[o] - m); s += logits[o]; }
        float inv = 1.f / s;
#pragma unroll
        for (int o = 0; o < NOUT; ++o) out[(size_t)r * NOUT + o] = logits[o] * inv;
    }
}

// ---------------------------------------------------------------------------
extern "C" void kernel_launch(void* const* d_in, const int* in_sizes, int n_in,
                              void* d_out, int out_size, void* d_ws, size_t ws_size,
                              hipStream_t stream) {
    const float* x  = (const float*)d_in[0];
    const float* W  = (const float*)d_in[1];
    const float* U  = (const float*)d_in[2];
    const float* b  = (const float*)d_in[3];
    const float* Wd = (const float*)d_in[4];
    const float* bd = (const float*)d_in[5];
    float* out = (float*)d_out;

    __hip_bfloat16* xw = (__hip_bfloat16*)d_ws;
    float* hbuf = (float*)((char*)d_ws + (size_t)Bsz * Tt * G4 * sizeof(__hip_bfloat16));

    k1_xw<<<(Bsz * Tt) / RB, 256, 0, stream>>>(x, W, b, xw);
    k2_scan<<<Bsz, 256, 0, stream>>>(xw, U, hbuf);
    k3_dense<<<1, 256, 0, stream>>>(hbuf, Wd, bd, out);
}

// Round 2
// 571.995 us; speedup vs baseline: 5.8445x; 5.8445x over previous
//
#include <hip/hip_runtime.h>
#include <hip/hip_bf16.h>

#define Hh   64      // LSTM hidden
#define G4   256     // 4*H gate width
#define Dd   128     // input feature dim
#define Bsz  256     // batch
#define Tt   1024    // time steps
#define NOUT 10      // dense classes

typedef __bf16  bf16x8 __attribute__((ext_vector_type(8)));
typedef float   f32x4v __attribute__((ext_vector_type(4)));

// ---------------------------------------------------------------------------
// K0: Wt[n][k] = bf16(W[k][n])  (transpose + convert, 32K elems, trivial)
// ---------------------------------------------------------------------------
__global__ __launch_bounds__(128)
void k0_wt(const float* __restrict__ W, __bf16* __restrict__ Wt) {
    const int n = blockIdx.x;    // 0..255 (gate col)
    const int k = threadIdx.x;   // 0..127 (input dim)
    Wt[(size_t)n * Dd + k] = (__bf16)W[(size_t)k * G4 + n];
}

// ---------------------------------------------------------------------------
// K1: xw = x @ W + b via mfma_f32_16x16x32_bf16.
// Block = 256 thr (4 waves) = 128 rows x 256 cols. Wave w owns cols
// [64w,64w+64): B-frags (4 col-tiles x 4 k-steps) held in 64 VGPRs for the
// whole block. A loaded fp32 global -> cvt bf16 -> frag (no LDS).
// A-frag: lane l holds A[row=l&15][k=(l>>4)*8 + j]; B-frag: col=l&15, same k.
// D: col=l&15, row=(l>>4)*4+reg  [m89-verified].
// ---------------------------------------------------------------------------
#define K1_RT 8   // 16-row tiles per block -> 128 rows/block

__global__ __launch_bounds__(256)
void k1_mfma(const float* __restrict__ x, const __bf16* __restrict__ Wt,
             const float* __restrict__ bias, __bf16* __restrict__ xw) {
    const int tid = threadIdx.x;
    const int w   = tid >> 6;      // wave 0..3
    const int l   = tid & 63;
    const int r16 = l & 15;
    const int kq  = l >> 4;        // 0..3
    const size_t rowbase = (size_t)blockIdx.x * (16 * K1_RT);

    bf16x8 bfr[4][4];
    float  bval[4];
#pragma unroll
    for (int ct = 0; ct < 4; ++ct) {
        const int col = w * 64 + ct * 16 + r16;
        const __bf16* wp = Wt + (size_t)col * Dd + kq * 8;
#pragma unroll
        for (int kk = 0; kk < 4; ++kk)
            bfr[ct][kk] = *(const bf16x8*)(wp + kk * 32);
        bval[ct] = bias[col];
    }

    for (int rt = 0; rt < K1_RT; ++rt) {
        const size_t arow = rowbase + rt * 16 + r16;
        const float* xr = x + arow * Dd + kq * 8;
        bf16x8 afr[4];
#pragma unroll
        for (int kk = 0; kk < 4; ++kk) {
            const float4 lo = *(const float4*)(xr + kk * 32);
            const float4 hi = *(const float4*)(xr + kk * 32 + 4);
            afr[kk][0] = (__bf16)lo.x; afr[kk][1] = (__bf16)lo.y;
            afr[kk][2] = (__bf16)lo.z; afr[kk][3] = (__bf16)lo.w;
            afr[kk][4] = (__bf16)hi.x; afr[kk][5] = (__bf16)hi.y;
            afr[kk][6] = (__bf16)hi.z; afr[kk][7] = (__bf16)hi.w;
        }
        f32x4v acc[4];
#pragma unroll
        for (int ct = 0; ct < 4; ++ct)
            acc[ct] = (f32x4v){bval[ct], bval[ct], bval[ct], bval[ct]};
#pragma unroll
        for (int ct = 0; ct < 4; ++ct)
#pragma unroll
            for (int kk = 0; kk < 4; ++kk)
                acc[ct] = __builtin_amdgcn_mfma_f32_16x16x32_bf16(
                              afr[kk], bfr[ct][kk], acc[ct], 0, 0, 0);

        const size_t orow0 = rowbase + rt * 16 + kq * 4;
#pragma unroll
        for (int ct = 0; ct < 4; ++ct) {
            const int col = w * 64 + ct * 16 + r16;
#pragma unroll
            for (int r = 0; r < 4; ++r)
                xw[(orow0 + r) * G4 + col] = (__bf16)acc[ct][r];
        }
    }
}

// ---------------------------------------------------------------------------
// K2: sequential LSTM scan. One workgroup (256 threads) per batch row.
// Thread g owns U column g (64 VGPRs). h broadcast via LDS float4 reads
// (16 ds_read_b128 instead of 64 b32); z operand prefetched one step ahead.
// ---------------------------------------------------------------------------
__global__ __launch_bounds__(256)
void k2_scan(const __bf16* __restrict__ xw, const float* __restrict__ U,
             float* __restrict__ hout) {
    const int g = threadIdx.x;
    const int brow = blockIdx.x;

    __shared__ __align__(16) float hs[Hh];
    __shared__ float zs[G4];

    float u[Hh];
#pragma unroll
    for (int j = 0; j < Hh; ++j) u[j] = U[(size_t)j * G4 + g];

    float c = 0.f;
    if (g < Hh) hs[g] = 0.f;

    const __bf16* __restrict__ xwcol = xw + (size_t)brow * Tt * G4 + g;
    float zin = (float)xwcol[0];
    __syncthreads();

    for (int t = 0; t < Tt; ++t) {
        const int tn = (t + 1 < Tt) ? (t + 1) : (Tt - 1);
        const float znext = (float)xwcol[(size_t)tn * G4];  // prefetch, used next iter
        float a0 = zin, a1 = 0.f, a2 = 0.f, a3 = 0.f;
#pragma unroll
        for (int j = 0; j < Hh; j += 4) {
            const f32x4v h4 = *(const f32x4v*)&hs[j];
            a0 = fmaf(h4[0], u[j + 0], a0);
            a1 = fmaf(h4[1], u[j + 1], a1);
            a2 = fmaf(h4[2], u[j + 2], a2);
            a3 = fmaf(h4[3], u[j + 3], a3);
        }
        zs[g] = (a0 + a1) + (a2 + a3);
        __syncthreads();
        if (g < Hh) {
            const float zi = zs[g], zf = zs[Hh + g], zg = zs[2 * Hh + g], zo = zs[3 * Hh + g];
            const float gi = fminf(fmaxf(0.2f * zi + 0.5f, 0.f), 1.f);
            const float gf = fminf(fmaxf(0.2f * zf + 0.5f, 0.f), 1.f);
            const float gg = fmaxf(zg, 0.f);
            const float go = fminf(fmaxf(0.2f * zo + 0.5f, 0.f), 1.f);
            c = gf * c + gi * gg;
            hs[g] = go * fmaxf(c, 0.f);
        }
        zin = znext;
        __syncthreads();
    }
    if (g < Hh) hout[(size_t)brow * Hh + g] = hs[g];
}

// ---------------------------------------------------------------------------
// K3: out[r,:] = softmax(h[r,:] @ Wd + bd). One block, thread = batch row.
// ---------------------------------------------------------------------------
__global__ __launch_bounds__(256)
void k3_dense(const float* __restrict__ hin, const float* __restrict__ Wd,
              const float* __restrict__ bd, float* __restrict__ out) {
    __shared__ float wd[Hh * NOUT];
    __shared__ float bds[NOUT];
    for (int i = threadIdx.x; i < Hh * NOUT; i += blockDim.x) wd[i] = Wd[i];
    if (threadIdx.x < NOUT) bds[threadIdx.x] = bd[threadIdx.x];
    __syncthreads();

    const int r = threadIdx.x;
    if (r < Bsz) {
        float hrow[Hh];
#pragma unroll
        for (int j = 0; j < Hh; ++j) hrow[j] = hin[(size_t)r * Hh + j];
        float logits[NOUT];
#pragma unroll
        for (int o = 0; o < NOUT; ++o) {
            float acc = bds[o];
#pragma unroll
            for (int j = 0; j < Hh; ++j) acc = fmaf(hrow[j], wd[j * NOUT + o], acc);
            logits[o] = acc;
        }
        float m = logits[0];
#pragma unroll
        for (int o = 1; o < NOUT; ++o) m = fmaxf(m, logits[o]);
        float s = 0.f;
#pragma unroll
        for (int o = 0; o < NOUT; ++o) { logits[o] = expf(logits[o] - m); s += logits[o]; }
        const float inv = 1.f / s;
#pragma unroll
        for (int o = 0; o < NOUT; ++o) out[(size_t)r * NOUT + o] = logits[o] * inv;
    }
}

// ---------------------------------------------------------------------------
extern "C" void kernel_launch(void* const* d_in, const int* in_sizes, int n_in,
                              void* d_out, int out_size, void* d_ws, size_t ws_size,
                              hipStream_t stream) {
    const float* x  = (const float*)d_in[0];
    const float* W  = (const float*)d_in[1];
    const float* U  = (const float*)d_in[2];
    const float* b  = (const float*)d_in[3];
    const float* Wd = (const float*)d_in[4];
    const float* bd = (const float*)d_in[5];
    float* out = (float*)d_out;

    const size_t xw_bytes = (size_t)Bsz * Tt * G4 * sizeof(__bf16);   // 128 MiB
    __bf16* xw   = (__bf16*)d_ws;
    float*  hbuf = (float*)((char*)d_ws + xw_bytes);
    __bf16* Wt   = (__bf16*)((char*)d_ws + xw_bytes + (size_t)Bsz * Hh * sizeof(float));

    k0_wt<<<G4, Dd, 0, stream>>>(W, Wt);
    k1_mfma<<<(Bsz * Tt) / (16 * K1_RT), 256, 0, stream>>>(x, Wt, b, xw);
    k2_scan<<<Bsz, 256, 0, stream>>>(xw, U, hbuf);
    k3_dense<<<1, 256, 0, stream>>>(hbuf, Wd, bd, out);
}